// Round 3
// baseline (250.965 us; speedup 1.0000x reference)
//
#include <hip/hip_runtime.h>
#include <hip/hip_bf16.h>

// Binarized-weight conv2d: x[32][256][56][56] (f32), W[256][256][3][3] (sign)
// -> out[32][256][56][56] (f32), stride 1, pad 1.
// bf16 MFMA implicit GEMM. M=100352 px, N=256 c_out, K=2304.
// R2: X-only LDS (W fragments loaded global->VGPR, L2-resident),
//     8-phase counted-vmcnt schedule, halo fused into transpose (no memset).

#define N_IMG   32
#define C_IN    256
#define C_OUT   256
#define HW      56
#define HP      58
#define PIX     (HW*HW)      // 3136
#define M_TOT   (N_IMG*PIX)  // 100352
#define K_TOT   (C_IN*9)     // 2304

#define WB_BYTES   (C_OUT * K_TOT * 2)
#define XPAD_ELEMS (N_IMG * HP * HP * C_IN)
#define XPAD_BYTES (XPAD_ELEMS * 2)
#define WS_NEEDED  (WB_BYTES + XPAD_BYTES)

#define BM      224
#define NBLK    (M_TOT / BM)   // 448 = 8*56
#define NT      36             // K tiles of 64

typedef short  bf16x8 __attribute__((ext_vector_type(8)));
typedef float  f32x4  __attribute__((ext_vector_type(4)));

// ---------------- W binarize + reorder: OIHW f32 -> [co][khkw*256+ci] bf16 (+-1)
__global__ void __launch_bounds__(256) binW_kernel(const float* __restrict__ W,
                                                   unsigned short* __restrict__ wb) {
    int i = blockIdx.x * 256 + threadIdx.x;
    int co = i / K_TOT;
    int k  = i - co * K_TOT;
    int khkw = k >> 8;
    int ci   = k & 255;
    float v = W[co * K_TOT + ci * 9 + khkw];
    wb[i] = (v >= 0.f) ? 0x3F80u : 0xBF80u;
}

// ---------------- x: f32 NCHW -> bf16 NHWC padded [n][h+1][w+1][ci], halo fused
__global__ void __launch_bounds__(256) transpose_pad_kernel(const float* __restrict__ x,
                                                            unsigned short* __restrict__ xp) {
    __shared__ __align__(16) unsigned short s[HW * 258];
    const int t = threadIdx.x;
    const int h = blockIdx.x;
    const int n = blockIdx.y;
    const float* xrow = x + ((n * C_IN) * HW + h) * HW;

    #pragma unroll 4
    for (int i = 0; i < 64; ++i) {
        int idx = i * 256 + t;
        int ci = idx >> 6, w = idx & 63;
        if (w < HW) {
            float v = xrow[ci * PIX + w];
            __hip_bfloat16 b = __float2bfloat16(v);
            s[w * 258 + ci] = reinterpret_cast<unsigned short&>(b);
        }
    }
    __syncthreads();
    #pragma unroll 4
    for (int i = 0; i < 28; ++i) {
        int idx = i * 256 + t;
        int w = idx >> 7, cp = idx & 127;
        unsigned int d = *(const unsigned int*)&s[w * 258 + cp * 2];
        unsigned int off = ((n * HP + h + 1) * HP + (w + 1)) * C_IN + cp * 2;
        *(unsigned int*)&xp[off] = d;
    }
    // ---- fused halo zeros (replaces global memset) ----
    // side columns wp=0 / wp=57 of this padded row (h+1): 256 ci = 128 dwords each
    if (t < 128) {
        *(unsigned int*)&xp[((n * HP + h + 1) * HP + 0)  * C_IN + t * 2] = 0u;
        *(unsigned int*)&xp[((n * HP + h + 1) * HP + 57) * C_IN + t * 2] = 0u;
    }
    // top row hp=0 (h==0 block) and bottom row hp=57 (h==55 block): 58*256 shorts
    if (h == 0) {
        unsigned int* row = (unsigned int*)&xp[(unsigned int)(n * HP + 0) * HP * C_IN];
        for (int i = t; i < HP * C_IN / 2; i += 256) row[i] = 0u;
    }
    if (h == HW - 1) {
        unsigned int* row = (unsigned int*)&xp[(unsigned int)(n * HP + 57) * HP * C_IN];
        for (int i = t; i < HP * C_IN / 2; i += 256) row[i] = 0u;
    }
}

// ---------------- 8-phase GEMM, X-only LDS
// LDS: 4 X halves [buf][kkhalf] of [256 rows][32 k] = 16KB each, 64KB total.
// swizzle: 16B chunk c within 64B row stored at physical chunk c ^ ((row>>1)&3).
#define XH(b,s)  (((b)*2+(s))*16384)

__device__ __forceinline__ int xko(int kabs) {       // im2col offset into xpad
    int khkw = kabs >> 8;                            // 0..8 (uniform)
    int kh = (khkw * 11) >> 5;                       // /3 for 0..8
    int kw = khkw - kh * 3;
    return (kh * HP + kw) * C_IN + (kabs & 255);
}

__global__ void __launch_bounds__(512, 2)
conv_gemm8_kernel(const __hip_bfloat16* __restrict__ xpad,
                  const __hip_bfloat16* __restrict__ wb,
                  float* __restrict__ out) {
    __shared__ __align__(16) unsigned short LDSBUF[32768];   // 64 KiB

    const int t    = threadIdx.x;
    const int lane = t & 63;
    const int wid  = t >> 6;
    const int wpx  = wid >> 2;       // 0..1 : 112-px half
    const int wco  = wid & 3;        // 0..3 : 64-co quarter
    const int l15  = lane & 15;
    const int l4   = lane >> 4;

    int bid = (int)blockIdx.x;
    bid = (bid & 7) * (NBLK / 8) + (bid >> 3);      // XCD swizzle (448 = 8*56)
    const int m0 = bid * BM;

    // read-side LDS byte offsets (within one 16KB half)
    int xrd[7];
    #pragma unroll
    for (int i = 0; i < 7; ++i) {
        int r = wpx * 112 + i * 16 + l15;
        xrd[i] = r * 64 + ((l4 ^ ((r >> 1) & 3)) << 4);
    }
    // W fragment global bases (element offsets; add kabs per phase)
    int wbase[4];
    #pragma unroll
    for (int j = 0; j < 4; ++j)
        wbase[j] = (wco * 64 + j * 16 + l15) * K_TOT + l4 * 8;

    // stage-side: issue I0 -> rows 0..127 (dest t*16), I1 -> rows 128..255 (dest 8192+t*16)
    const int lc8 = ((t & 3) ^ ((t >> 3) & 3)) << 3;     // inverse-swizzled k offset (elems)
    int rbA, rbB;
    {
        int rA = t >> 2;
        int rB = 128 + rA; if (rB > BM - 1) rB = BM - 1;   // rows 224..255: dup of 223, never read
        int mA = m0 + rA, mB = m0 + rB;
        int nA = mA / PIX, pA = mA - nA * PIX, hA = pA / HW, wA = pA - hA * HW;
        int nB = mB / PIX, pB = mB - nB * PIX, hB = pB / HW, wB2 = pB - hB * HW;
        rbA = ((nA * HP + hA) * HP + wA) * C_IN + lc8;
        rbB = ((nB * HP + hB) * HP + wB2) * C_IN + lc8;
    }

#define GLD(gp, off) __builtin_amdgcn_global_load_lds( \
        (const __attribute__((address_space(1))) void*)(gp), \
        (__attribute__((address_space(3))) void*)((char*)LDSBUF + (off)), 16, 0, 0)
#define STG0(b,s,ko) GLD(xpad + rbA + (ko), XH(b,s) + t * 16)
#define STG1(b,s,ko) GLD(xpad + rbB + (ko), XH(b,s) + 8192 + t * 16)
#define LDXF(i,b,s)  (*(const bf16x8*)((const char*)LDSBUF + XH(b,s) + xrd[i]))

    f32x4 acc[7][4];
    #pragma unroll
    for (int i = 0; i < 7; ++i)
        #pragma unroll
        for (int j = 0; j < 4; ++j)
            acc[i][j] = (f32x4){0.f, 0.f, 0.f, 0.f};

    bf16x8 w0[4], w1[4];             // W frag double-buffer (by kk parity)

    // PH0: frags 0-3, 16 MFMA, prefetch WD[0..1].  PH1: frags 4-6, 12 MFMA,
    // prefetch WD[2..3], then counted vmcnt(6) guarding the NEXT pair's LDS reads.
#define PH0(b, s, WU, WD, wk, STGE) { \
        bf16x8 xf[4]; \
        xf[0]=LDXF(0,b,s); xf[1]=LDXF(1,b,s); xf[2]=LDXF(2,b,s); xf[3]=LDXF(3,b,s); \
        WD[0] = *(const bf16x8*)(wb + wbase[0] + (wk)); \
        WD[1] = *(const bf16x8*)(wb + wbase[1] + (wk)); \
        STGE; \
        __builtin_amdgcn_sched_barrier(0); \
        __builtin_amdgcn_s_barrier(); \
        __builtin_amdgcn_s_setprio(1); \
        _Pragma("unroll") \
        for (int i_ = 0; i_ < 4; ++i_) \
            _Pragma("unroll") \
            for (int j_ = 0; j_ < 4; ++j_) \
                acc[i_][j_] = __builtin_amdgcn_mfma_f32_16x16x32_bf16(WU[j_], xf[i_], acc[i_][j_], 0, 0, 0); \
        __builtin_amdgcn_s_setprio(0); \
        __builtin_amdgcn_sched_barrier(0); \
        __builtin_amdgcn_s_barrier(); \
    }

#define PH1(b, s, WU, WD, wk, STGE) { \
        bf16x8 xf[3]; \
        xf[0]=LDXF(4,b,s); xf[1]=LDXF(5,b,s); xf[2]=LDXF(6,b,s); \
        WD[2] = *(const bf16x8*)(wb + wbase[2] + (wk)); \
        WD[3] = *(const bf16x8*)(wb + wbase[3] + (wk)); \
        STGE; \
        __builtin_amdgcn_sched_barrier(0); \
        __builtin_amdgcn_s_barrier(); \
        __builtin_amdgcn_s_setprio(1); \
        _Pragma("unroll") \
        for (int i_ = 0; i_ < 3; ++i_) \
            _Pragma("unroll") \
            for (int j_ = 0; j_ < 4; ++j_) \
                acc[4 + i_][j_] = __builtin_amdgcn_mfma_f32_16x16x32_bf16(WU[j_], xf[i_], acc[4 + i_][j_], 0, 0, 0); \
        __builtin_amdgcn_s_setprio(0); \
        asm volatile("s_waitcnt vmcnt(6)" ::: "memory"); \
        __builtin_amdgcn_sched_barrier(0); \
        __builtin_amdgcn_s_barrier(); \
    }

    // prologue: W(T0,kk0) -> w0; stage tile0 both halves -> buf0; drain; barrier
    w0[0] = *(const bf16x8*)(wb + wbase[0]);
    w0[1] = *(const bf16x8*)(wb + wbase[1]);
    w0[2] = *(const bf16x8*)(wb + wbase[2]);
    w0[3] = *(const bf16x8*)(wb + wbase[3]);
    {
        int ko0 = xko(0), ko1 = xko(32);
        STG0(0, 0, ko0); STG1(0, 0, ko0);
        STG0(0, 1, ko1); STG1(0, 1, ko1);
    }
    asm volatile("s_waitcnt vmcnt(0)" ::: "memory");
    __builtin_amdgcn_sched_barrier(0);
    __builtin_amdgcn_s_barrier();

    #pragma unroll 1
    for (int it = 0; it < NT / 2; ++it) {
        const int T0 = 2 * it, T1 = 2 * it + 1;
        int T2 = T0 + 2; if (T2 > NT - 1) T2 = NT - 1;     // clamped over-stage (never read)
        const int kW12 = T0 * 64 + 32;   // W for pair(T0,kk1) -> w1
        const int kW34 = T1 * 64;        // W for pair(T1,kk0) -> w0
        const int kW56 = T1 * 64 + 32;   // W for pair(T1,kk1) -> w1
        const int kW78 = T2 * 64;        // W for pair(T2,kk0) -> w0
        const int koA = xko(T1 * 64), koB = xko(T1 * 64 + 32);
        const int koC = xko(T2 * 64), koD = xko(T2 * 64 + 32);

        PH0(0, 0, w0, w1, kW12, STG0(1, 0, koA));   // ph1
        PH1(0, 0, w0, w1, kW12, STG1(1, 0, koA));   // ph2  vmcnt(6)
        PH0(0, 1, w1, w0, kW34, STG0(1, 1, koB));   // ph3
        PH1(0, 1, w1, w0, kW34, STG1(1, 1, koB));   // ph4  vmcnt(6)
        PH0(1, 0, w0, w1, kW56, STG0(0, 0, koC));   // ph5
        PH1(1, 0, w0, w1, kW56, STG1(0, 0, koC));   // ph6  vmcnt(6)
        PH0(1, 1, w1, w0, kW78, STG0(0, 1, koD));   // ph7
        PH1(1, 1, w1, w0, kW78, STG1(0, 1, koD));   // ph8  vmcnt(6)
    }

    // epilogue: C row=co (l4*4+r), col=px (l15)
    const int nimg = m0 / PIX;                // exact: 3136 = 14*224
    const int p0   = m0 - nimg * PIX;
    float* ob = out + nimg * (C_OUT * PIX);
    #pragma unroll
    for (int i = 0; i < 7; ++i) {
        int p = p0 + wpx * 112 + i * 16 + l15;
        #pragma unroll
        for (int j = 0; j < 4; ++j) {
            int co = wco * 64 + j * 16 + l4 * 4;
            #pragma unroll
            for (int r = 0; r < 4; ++r)
                ob[(co + r) * PIX + p] = acc[i][j][r];
        }
    }
#undef PH0
#undef PH1
#undef GLD
#undef STG0
#undef STG1
#undef LDXF
}

// ---------------- fallback: naive direct conv
__global__ void __launch_bounds__(256) conv_naive_kernel(const float* __restrict__ x,
                                                         const float* __restrict__ W,
                                                         float* __restrict__ out) {
    int idx = blockIdx.x * 256 + threadIdx.x;
    int w = idx % HW;
    int tmp = idx / HW;
    int h = tmp % HW;
    tmp /= HW;
    int co = tmp & 255;
    int n  = tmp >> 8;
    const float* xn = x + n * (C_IN * PIX);
    const float* wc = W + co * K_TOT;
    float acc = 0.f;
    for (int ci = 0; ci < C_IN; ++ci) {
        const float* xc = xn + ci * PIX;
        const float* wk = wc + ci * 9;
        #pragma unroll
        for (int kh = 0; kh < 3; ++kh) {
            int hh = h + kh - 1;
            if (hh < 0 || hh >= HW) continue;
            #pragma unroll
            for (int kw = 0; kw < 3; ++kw) {
                int ww = w + kw - 1;
                if (ww < 0 || ww >= HW) continue;
                float xv = xc[hh * HW + ww];
                acc += (wk[kh * 3 + kw] >= 0.f) ? xv : -xv;
            }
        }
    }
    out[idx] = acc;
}

extern "C" void kernel_launch(void* const* d_in, const int* in_sizes, int n_in,
                              void* d_out, int out_size, void* d_ws, size_t ws_size,
                              hipStream_t stream) {
    const float* x = (const float*)d_in[0];
    const float* W = (const float*)d_in[1];
    float* out = (float*)d_out;

    if (ws_size < (size_t)WS_NEEDED) {
        int total = N_IMG * C_OUT * PIX;
        conv_naive_kernel<<<(total + 255) / 256, 256, 0, stream>>>(x, W, out);
        return;
    }

    unsigned short* wb   = (unsigned short*)d_ws;
    __hip_bfloat16* xpad = (__hip_bfloat16*)((char*)d_ws + WB_BYTES);

    binW_kernel<<<(C_OUT * K_TOT) / 256, 256, 0, stream>>>(W, wb);
    transpose_pad_kernel<<<dim3(HW, N_IMG), 256, 0, stream>>>(x, (unsigned short*)xpad);
    conv_gemm8_kernel<<<dim3(NBLK), 512, 0, stream>>>(xpad, (const __hip_bfloat16*)wb, out);
}

// Round 4
// 148.453 us; speedup vs baseline: 1.6905x; 1.6905x over previous
//
#include <hip/hip_runtime.h>
#include <hip/hip_bf16.h>

// Binarized-weight conv2d: x[32][256][56][56] (f32), W[256][256][3][3] (sign)
// -> out[32][256][56][56] (f32), stride 1, pad 1.
// bf16 MFMA implicit GEMM. M=100352 px, N=256 c_out, K=2304.
// R4: R1 structure (X+W in LDS, counted vmcnt, swizzle, setprio) but
//     1 barrier per phase, 28 MFMA per phase (2 phases per K-tile of 64),
//     uniform vmcnt(4), fused-halo transpose (no memset).

#define N_IMG   32
#define C_IN    256
#define C_OUT   256
#define HW      56
#define HP      58
#define PIX     (HW*HW)      // 3136
#define M_TOT   (N_IMG*PIX)  // 100352
#define K_TOT   (C_IN*9)     // 2304

#define WB_BYTES   (C_OUT * K_TOT * 2)
#define XPAD_ELEMS (N_IMG * HP * HP * C_IN)
#define XPAD_BYTES (XPAD_ELEMS * 2)
#define WS_NEEDED  (WB_BYTES + XPAD_BYTES)

#define BM      224
#define NBLK    (M_TOT / BM)   // 448 = 8*56
#define NT      36             // K tiles of 64

typedef short  bf16x8 __attribute__((ext_vector_type(8)));
typedef float  f32x4  __attribute__((ext_vector_type(4)));

// ---------------- W binarize + reorder: OIHW f32 -> [co][khkw*256+ci] bf16 (+-1)
__global__ void __launch_bounds__(256) binW_kernel(const float* __restrict__ W,
                                                   unsigned short* __restrict__ wb) {
    int i = blockIdx.x * 256 + threadIdx.x;
    int co = i / K_TOT;
    int k  = i - co * K_TOT;
    int khkw = k >> 8;
    int ci   = k & 255;
    float v = W[co * K_TOT + ci * 9 + khkw];
    wb[i] = (v >= 0.f) ? 0x3F80u : 0xBF80u;
}

// ---------------- x: f32 NCHW -> bf16 NHWC padded [n][h+1][w+1][ci], halo fused
__global__ void __launch_bounds__(256) transpose_pad_kernel(const float* __restrict__ x,
                                                            unsigned short* __restrict__ xp) {
    __shared__ __align__(16) unsigned short s[HW * 258];
    const int t = threadIdx.x;
    const int h = blockIdx.x;
    const int n = blockIdx.y;
    const float* xrow = x + ((n * C_IN) * HW + h) * HW;

    #pragma unroll 4
    for (int i = 0; i < 64; ++i) {
        int idx = i * 256 + t;
        int ci = idx >> 6, w = idx & 63;
        if (w < HW) {
            float v = xrow[ci * PIX + w];
            __hip_bfloat16 b = __float2bfloat16(v);
            s[w * 258 + ci] = reinterpret_cast<unsigned short&>(b);
        }
    }
    __syncthreads();
    #pragma unroll 4
    for (int i = 0; i < 28; ++i) {
        int idx = i * 256 + t;
        int w = idx >> 7, cp = idx & 127;
        unsigned int d = *(const unsigned int*)&s[w * 258 + cp * 2];
        unsigned int off = ((n * HP + h + 1) * HP + (w + 1)) * C_IN + cp * 2;
        *(unsigned int*)&xp[off] = d;
    }
    // fused halo zeros (replaces global memset)
    if (t < 128) {
        *(unsigned int*)&xp[((n * HP + h + 1) * HP + 0)  * C_IN + t * 2] = 0u;
        *(unsigned int*)&xp[((n * HP + h + 1) * HP + 57) * C_IN + t * 2] = 0u;
    }
    if (h == 0) {
        unsigned int* row = (unsigned int*)&xp[(unsigned int)(n * HP + 0) * HP * C_IN];
        for (int i = t; i < HP * C_IN / 2; i += 256) row[i] = 0u;
    }
    if (h == HW - 1) {
        unsigned int* row = (unsigned int*)&xp[(unsigned int)(n * HP + 57) * HP * C_IN];
        for (int i = t; i < HP * C_IN / 2; i += 256) row[i] = 0u;
    }
}

// ---------------- GEMM: regions [parity][khalf] of [256 rows][32 k] = 16KB.
// X at XH, W at WH. swizzle: 16B chunk c of 64B row at physical c ^ ((row>>1)&3).
#define XH(b,s)  (((b)*2+(s))*16384)
#define WH(b,s)  (65536 + ((b)*2+(s))*16384)

__device__ __forceinline__ int xko(int kabs) {       // im2col offset into xpad
    int khkw = kabs >> 8;                            // 0..8 (uniform)
    int kh = (khkw * 11) >> 5;                       // /3 for 0..8
    int kw = khkw - kh * 3;
    return (kh * HP + kw) * C_IN + (kabs & 255);
}

__global__ void __launch_bounds__(512, 2)
conv_gemm_kernel(const __hip_bfloat16* __restrict__ xpad,
                 const __hip_bfloat16* __restrict__ wb,
                 float* __restrict__ out) {
    __shared__ __align__(16) unsigned short LDSBUF[65536];   // 128 KiB

    const int t    = threadIdx.x;
    const int lane = t & 63;
    const int wid  = t >> 6;
    const int wpx  = wid >> 2;       // 0..1 : 112-px half
    const int wco  = wid & 3;        // 0..3 : 64-co quarter
    const int l15  = lane & 15;
    const int l4   = lane >> 4;

    int bid = (int)blockIdx.x;
    bid = (bid & 7) * (NBLK / 8) + (bid >> 3);      // XCD swizzle (448 = 8*56)
    const int m0 = bid * BM;

    // read-side LDS byte offsets (within one 16KB region)
    int xrd[7], wrd[4];
    #pragma unroll
    for (int i = 0; i < 7; ++i) {
        int r = wpx * 112 + i * 16 + l15;
        xrd[i] = r * 64 + ((l4 ^ ((r >> 1) & 3)) << 4);
    }
    #pragma unroll
    for (int j = 0; j < 4; ++j) {
        int r = wco * 64 + j * 16 + l15;
        wrd[j] = r * 64 + ((l4 ^ ((r >> 1) & 3)) << 4);
    }

    // stage-side: issue0 -> rows 0..127 (dest t*16), issue1 -> rows 128..255 (+8192)
    const int lc8 = ((t & 3) ^ ((t >> 3) & 3)) << 3;     // inverse-swizzled k offset (elems)
    int rbA, rbB;
    {
        int rA = t >> 2;
        int rB = 128 + rA; if (rB > BM - 1) rB = BM - 1;   // rows 224..255: dup, never read
        int mA = m0 + rA, mB = m0 + rB;
        int nA = mA / PIX, pA = mA - nA * PIX, hA = pA / HW, wA = pA - hA * HW;
        int nB = mB / PIX, pB = mB - nB * PIX, hB = pB / HW, wB2 = pB - hB * HW;
        rbA = ((nA * HP + hA) * HP + wA) * C_IN + lc8;
        rbB = ((nB * HP + hB) * HP + wB2) * C_IN + lc8;
    }
    int wgA, wgB;
    {
        int rA = t >> 2;
        wgA = rA * K_TOT + lc8;
        wgB = (128 + rA) * K_TOT + lc8;
    }

#define GLD(gp, off) __builtin_amdgcn_global_load_lds( \
        (const __attribute__((address_space(1))) void*)(gp), \
        (__attribute__((address_space(3))) void*)((char*)LDSBUF + (off)), 16, 0, 0)
#define STGX(b,s,ko) { GLD(xpad + rbA + (ko), XH(b,s) + t * 16); \
                       GLD(xpad + rbB + (ko), XH(b,s) + 8192 + t * 16); }
#define STGW(b,s,ka) { GLD(wb + wgA + (ka), WH(b,s) + t * 16); \
                       GLD(wb + wgB + (ka), WH(b,s) + 8192 + t * 16); }
#define LDXF(i,b,s)  (*(const bf16x8*)((const char*)LDSBUF + XH(b,s) + xrd[i]))
#define LDWF(j,b,s)  (*(const bf16x8*)((const char*)LDSBUF + WH(b,s) + wrd[j]))

    f32x4 acc[7][4];
    #pragma unroll
    for (int i = 0; i < 7; ++i)
        #pragma unroll
        for (int j = 0; j < 4; ++j)
            acc[i][j] = (f32x4){0.f, 0.f, 0.f, 0.f};

    // One phase = one (tile parity b, k-half s): 11 ds_read + 4 stage GLD +
    // 28 MFMA + vmcnt(4) + single barrier. Stage target region [b^1][s] was
    // last read 2 phases ago (barrier-separated). Reads of phase p are staged
    // at p-2 and guarded by the vmcnt(4)+barrier at end of p-1 (in-order
    // retirement: outstanding 8 -> retire the 4 oldest = p-2's stages).
#define PHASE(b, s, koX, kW) { \
        bf16x8 xf[7], wf[4]; \
        _Pragma("unroll") \
        for (int i_ = 0; i_ < 7; ++i_) xf[i_] = LDXF(i_, b, s); \
        _Pragma("unroll") \
        for (int j_ = 0; j_ < 4; ++j_) wf[j_] = LDWF(j_, b, s); \
        STGX((b) ^ 1, s, koX); \
        STGW((b) ^ 1, s, kW); \
        __builtin_amdgcn_s_setprio(1); \
        _Pragma("unroll") \
        for (int i_ = 0; i_ < 7; ++i_) \
            _Pragma("unroll") \
            for (int j_ = 0; j_ < 4; ++j_) \
                acc[i_][j_] = __builtin_amdgcn_mfma_f32_16x16x32_bf16(wf[j_], xf[i_], acc[i_][j_], 0, 0, 0); \
        __builtin_amdgcn_s_setprio(0); \
        asm volatile("s_waitcnt vmcnt(4)" ::: "memory"); \
        __builtin_amdgcn_sched_barrier(0); \
        __builtin_amdgcn_s_barrier(); \
        __builtin_amdgcn_sched_barrier(0); \
    }

    // prologue: stage T0 kh0 (4 GLD) then T0 kh1 (4 GLD); retire kh0; barrier
    {
        int ko0 = xko(0), ko1 = xko(32);
        STGX(0, 0, ko0); STGW(0, 0, 0);
        STGX(0, 1, ko1); STGW(0, 1, 32);
    }
    asm volatile("s_waitcnt vmcnt(4)" ::: "memory");
    __builtin_amdgcn_sched_barrier(0);
    __builtin_amdgcn_s_barrier();
    __builtin_amdgcn_sched_barrier(0);

    #pragma unroll 1
    for (int it = 0; it < NT / 2; ++it) {
        const int T1 = 2 * it + 1;
        int T2 = 2 * it + 2; if (T2 > NT - 1) T2 = NT - 1;   // clamped over-stage
        PHASE(0, 0, xko(T1 * 64),      T1 * 64);        // P0(T0): stage (T1,kh0)
        PHASE(0, 1, xko(T1 * 64 + 32), T1 * 64 + 32);   // P1(T0): stage (T1,kh1)
        PHASE(1, 0, xko(T2 * 64),      T2 * 64);        // P0(T1): stage (T2,kh0)
        PHASE(1, 1, xko(T2 * 64 + 32), T2 * 64 + 32);   // P1(T1): stage (T2,kh1)
    }

    // epilogue: C row=co (l4*4+r), col=px (l15)
    const int nimg = m0 / PIX;                // exact: 3136 = 14*224
    const int p0   = m0 - nimg * PIX;
    float* ob = out + nimg * (C_OUT * PIX);
    #pragma unroll
    for (int i = 0; i < 7; ++i) {
        int p = p0 + wpx * 112 + i * 16 + l15;
        #pragma unroll
        for (int j = 0; j < 4; ++j) {
            int co = wco * 64 + j * 16 + l4 * 4;
            #pragma unroll
            for (int r = 0; r < 4; ++r)
                ob[(co + r) * PIX + p] = acc[i][j][r];
        }
    }
#undef PHASE
#undef GLD
#undef STGX
#undef STGW
#undef LDXF
#undef LDWF
}

// ---------------- fallback: naive direct conv
__global__ void __launch_bounds__(256) conv_naive_kernel(const float* __restrict__ x,
                                                         const float* __restrict__ W,
                                                         float* __restrict__ out) {
    int idx = blockIdx.x * 256 + threadIdx.x;
    int w = idx % HW;
    int tmp = idx / HW;
    int h = tmp % HW;
    tmp /= HW;
    int co = tmp & 255;
    int n  = tmp >> 8;
    const float* xn = x + n * (C_IN * PIX);
    const float* wc = W + co * K_TOT;
    float acc = 0.f;
    for (int ci = 0; ci < C_IN; ++ci) {
        const float* xc = xn + ci * PIX;
        const float* wk = wc + ci * 9;
        #pragma unroll
        for (int kh = 0; kh < 3; ++kh) {
            int hh = h + kh - 1;
            if (hh < 0 || hh >= HW) continue;
            #pragma unroll
            for (int kw = 0; kw < 3; ++kw) {
                int ww = w + kw - 1;
                if (ww < 0 || ww >= HW) continue;
                float xv = xc[hh * HW + ww];
                acc += (wk[kh * 3 + kw] >= 0.f) ? xv : -xv;
            }
        }
    }
    out[idx] = acc;
}

extern "C" void kernel_launch(void* const* d_in, const int* in_sizes, int n_in,
                              void* d_out, int out_size, void* d_ws, size_t ws_size,
                              hipStream_t stream) {
    const float* x = (const float*)d_in[0];
    const float* W = (const float*)d_in[1];
    float* out = (float*)d_out;

    if (ws_size < (size_t)WS_NEEDED) {
        int total = N_IMG * C_OUT * PIX;
        conv_naive_kernel<<<(total + 255) / 256, 256, 0, stream>>>(x, W, out);
        return;
    }

    unsigned short* wb   = (unsigned short*)d_ws;
    __hip_bfloat16* xpad = (__hip_bfloat16*)((char*)d_ws + WB_BYTES);

    binW_kernel<<<(C_OUT * K_TOT) / 256, 256, 0, stream>>>(W, wb);
    transpose_pad_kernel<<<dim3(HW, N_IMG), 256, 0, stream>>>(x, (unsigned short*)xpad);
    conv_gemm_kernel<<<dim3(NBLK), 512, 0, stream>>>(xpad, (const __hip_bfloat16*)wb, out);
}

// Round 5
// 142.534 us; speedup vs baseline: 1.7607x; 1.0415x over previous
//
#include <hip/hip_runtime.h>
#include <hip/hip_bf16.h>

// Binarized-weight conv2d: x[32][256][56][56] (f32), W[256][256][3][3] (sign)
// -> out[32][256][56][56] (f32), stride 1, pad 1.
// bf16 MFMA implicit GEMM. M=100352 px, N=256 c_out, K=2304.
// R5: m201-style micro-phases: 8 sub-phases per K-pair, each
//     {reads -> stage 1 region -> barrier -> lgkmcnt(0) -> 16/12 MFMA -> vmcnt(6)}.
//     One barrier/phase (stage map keeps >=2-phase separation), W frags reused
//     across ih-halves. Addressing identical to R4.

#define N_IMG   32
#define C_IN    256
#define C_OUT   256
#define HW      56
#define HP      58
#define PIX     (HW*HW)      // 3136
#define M_TOT   (N_IMG*PIX)  // 100352
#define K_TOT   (C_IN*9)     // 2304

#define WB_BYTES   (C_OUT * K_TOT * 2)
#define XPAD_ELEMS (N_IMG * HP * HP * C_IN)
#define XPAD_BYTES (XPAD_ELEMS * 2)
#define WS_NEEDED  (WB_BYTES + XPAD_BYTES)

#define BM      224
#define NBLK    (M_TOT / BM)   // 448 = 8*56
#define NT      36             // K tiles of 64

typedef short  bf16x8 __attribute__((ext_vector_type(8)));
typedef float  f32x4  __attribute__((ext_vector_type(4)));

// ---------------- W binarize + reorder: OIHW f32 -> [co][khkw*256+ci] bf16 (+-1)
__global__ void __launch_bounds__(256) binW_kernel(const float* __restrict__ W,
                                                   unsigned short* __restrict__ wb) {
    int i = blockIdx.x * 256 + threadIdx.x;
    int co = i / K_TOT;
    int k  = i - co * K_TOT;
    int khkw = k >> 8;
    int ci   = k & 255;
    float v = W[co * K_TOT + ci * 9 + khkw];
    wb[i] = (v >= 0.f) ? 0x3F80u : 0xBF80u;
}

// ---------------- x: f32 NCHW -> bf16 NHWC padded [n][h+1][w+1][ci], halo fused
__global__ void __launch_bounds__(256) transpose_pad_kernel(const float* __restrict__ x,
                                                            unsigned short* __restrict__ xp) {
    __shared__ __align__(16) unsigned short s[HW * 258];
    const int t = threadIdx.x;
    const int h = blockIdx.x;
    const int n = blockIdx.y;
    const float* xrow = x + ((n * C_IN) * HW + h) * HW;

    #pragma unroll 4
    for (int i = 0; i < 64; ++i) {
        int idx = i * 256 + t;
        int ci = idx >> 6, w = idx & 63;
        if (w < HW) {
            float v = xrow[ci * PIX + w];
            __hip_bfloat16 b = __float2bfloat16(v);
            s[w * 258 + ci] = reinterpret_cast<unsigned short&>(b);
        }
    }
    __syncthreads();
    #pragma unroll 4
    for (int i = 0; i < 28; ++i) {
        int idx = i * 256 + t;
        int w = idx >> 7, cp = idx & 127;
        unsigned int d = *(const unsigned int*)&s[w * 258 + cp * 2];
        unsigned int off = ((n * HP + h + 1) * HP + (w + 1)) * C_IN + cp * 2;
        *(unsigned int*)&xp[off] = d;
    }
    // fused halo zeros (replaces global memset)
    if (t < 128) {
        *(unsigned int*)&xp[((n * HP + h + 1) * HP + 0)  * C_IN + t * 2] = 0u;
        *(unsigned int*)&xp[((n * HP + h + 1) * HP + 57) * C_IN + t * 2] = 0u;
    }
    if (h == 0) {
        unsigned int* row = (unsigned int*)&xp[(unsigned int)(n * HP + 0) * HP * C_IN];
        for (int i = t; i < HP * C_IN / 2; i += 256) row[i] = 0u;
    }
    if (h == HW - 1) {
        unsigned int* row = (unsigned int*)&xp[(unsigned int)(n * HP + 57) * HP * C_IN];
        for (int i = t; i < HP * C_IN / 2; i += 256) row[i] = 0u;
    }
}

// ---------------- GEMM: regions [parity][khalf] of [256 rows][32 k] = 16KB.
// X at XH, W at WH. swizzle: 16B chunk c of 64B row at physical c ^ ((row>>1)&3).
#define XH(b,s)  (((b)*2+(s))*16384)
#define WH(b,s)  (65536 + ((b)*2+(s))*16384)

__device__ __forceinline__ int xko(int kabs) {       // im2col offset into xpad
    int khkw = kabs >> 8;                            // 0..8 (uniform)
    int kh = (khkw * 11) >> 5;                       // /3 for 0..8
    int kw = khkw - kh * 3;
    return (kh * HP + kw) * C_IN + (kabs & 255);
}

__global__ void __launch_bounds__(512, 2)
conv_gemm_kernel(const __hip_bfloat16* __restrict__ xpad,
                 const __hip_bfloat16* __restrict__ wb,
                 float* __restrict__ out) {
    __shared__ __align__(16) unsigned short LDSBUF[65536];   // 128 KiB

    const int t    = threadIdx.x;
    const int lane = t & 63;
    const int wid  = t >> 6;
    const int wpx  = wid >> 2;       // 0..1 : 112-px half
    const int wco  = wid & 3;        // 0..3 : 64-co quarter
    const int l15  = lane & 15;
    const int l4   = lane >> 4;

    int bid = (int)blockIdx.x;
    bid = (bid & 7) * (NBLK / 8) + (bid >> 3);      // XCD swizzle (448 = 8*56)
    const int m0 = bid * BM;

    // read-side LDS byte offsets (within one 16KB region)
    int xrd[7], wrd[4];
    #pragma unroll
    for (int i = 0; i < 7; ++i) {
        int r = wpx * 112 + i * 16 + l15;
        xrd[i] = r * 64 + ((l4 ^ ((r >> 1) & 3)) << 4);
    }
    #pragma unroll
    for (int j = 0; j < 4; ++j) {
        int r = wco * 64 + j * 16 + l15;
        wrd[j] = r * 64 + ((l4 ^ ((r >> 1) & 3)) << 4);
    }

    // stage-side: issue0 -> rows 0..127 (dest t*16), issue1 -> rows 128..255 (+8192)
    const int lc8 = ((t & 3) ^ ((t >> 3) & 3)) << 3;     // inverse-swizzled k offset (elems)
    int rbA, rbB;
    {
        int rA = t >> 2;
        int rB = 128 + rA; if (rB > BM - 1) rB = BM - 1;   // rows 224..255: dup, never read
        int mA = m0 + rA, mB = m0 + rB;
        int nA = mA / PIX, pA = mA - nA * PIX, hA = pA / HW, wA = pA - hA * HW;
        int nB = mB / PIX, pB = mB - nB * PIX, hB = pB / HW, wB2 = pB - hB * HW;
        rbA = ((nA * HP + hA) * HP + wA) * C_IN + lc8;
        rbB = ((nB * HP + hB) * HP + wB2) * C_IN + lc8;
    }
    int wgA, wgB;
    {
        int rA = t >> 2;
        wgA = rA * K_TOT + lc8;
        wgB = (128 + rA) * K_TOT + lc8;
    }

#define GLD(gp, off) __builtin_amdgcn_global_load_lds( \
        (const __attribute__((address_space(1))) void*)(gp), \
        (__attribute__((address_space(3))) void*)((char*)LDSBUF + (off)), 16, 0, 0)
#define STGX(b,s,ko) { GLD(xpad + rbA + (ko), XH(b,s) + t * 16); \
                       GLD(xpad + rbB + (ko), XH(b,s) + 8192 + t * 16); }
#define STGW(b,s,ka) { GLD(wb + wgA + (ka), WH(b,s) + t * 16); \
                       GLD(wb + wgB + (ka), WH(b,s) + 8192 + t * 16); }
#define LDXF(i,b,s)  (*(const bf16x8*)((const char*)LDSBUF + XH(b,s) + xrd[i]))
#define LDWF(j,b,s)  (*(const bf16x8*)((const char*)LDSBUF + WH(b,s) + wrd[j]))

    f32x4 acc[7][4];
    #pragma unroll
    for (int i = 0; i < 7; ++i)
        #pragma unroll
        for (int j = 0; j < 4; ++j)
            acc[i][j] = (f32x4){0.f, 0.f, 0.f, 0.f};

    bf16x8 wf[4];   // W frags, read in A-phase, reused in B-phase

    // Sub-phase pair per (b,s): A = {4 X frags (i0-3) + 4 W frags, 16 MFMA},
    //                           B = {3 X frags (i4-6), 12 MFMA, wf reuse}.
    // Each phase: reads, stage one 16KB region (2 GLD), s_barrier, lgkmcnt(0)
    // (read latency absorbed by barrier wait), MFMA cluster, vmcnt(6).
    // Stage map gives every target >=2 phases past last read; every read's
    // data staged >=4 phases earlier => vmcnt(6) retires it (2 GLD/phase).
#define SYNC_TOP  __builtin_amdgcn_sched_barrier(0); \
                  __builtin_amdgcn_s_barrier(); \
                  asm volatile("s_waitcnt lgkmcnt(0)" ::: "memory"); \
                  __builtin_amdgcn_sched_barrier(0)
#define SYNC_BOT  asm volatile("s_waitcnt vmcnt(6)" ::: "memory"); \
                  __builtin_amdgcn_sched_barrier(0)

#define PH_A(b, s, STGE) { \
        bf16x8 xf[4]; \
        xf[0]=LDXF(0,b,s); xf[1]=LDXF(1,b,s); xf[2]=LDXF(2,b,s); xf[3]=LDXF(3,b,s); \
        wf[0]=LDWF(0,b,s); wf[1]=LDWF(1,b,s); wf[2]=LDWF(2,b,s); wf[3]=LDWF(3,b,s); \
        STGE; \
        SYNC_TOP; \
        __builtin_amdgcn_s_setprio(1); \
        _Pragma("unroll") \
        for (int i_ = 0; i_ < 4; ++i_) \
            _Pragma("unroll") \
            for (int j_ = 0; j_ < 4; ++j_) \
                acc[i_][j_] = __builtin_amdgcn_mfma_f32_16x16x32_bf16(wf[j_], xf[i_], acc[i_][j_], 0, 0, 0); \
        __builtin_amdgcn_s_setprio(0); \
        SYNC_BOT; \
    }

#define PH_B(b, s, STGE) { \
        bf16x8 xf[3]; \
        xf[0]=LDXF(4,b,s); xf[1]=LDXF(5,b,s); xf[2]=LDXF(6,b,s); \
        STGE; \
        SYNC_TOP; \
        __builtin_amdgcn_s_setprio(1); \
        _Pragma("unroll") \
        for (int i_ = 0; i_ < 3; ++i_) \
            _Pragma("unroll") \
            for (int j_ = 0; j_ < 4; ++j_) \
                acc[4 + i_][j_] = __builtin_amdgcn_mfma_f32_16x16x32_bf16(wf[j_], xf[i_], acc[4 + i_][j_], 0, 0, 0); \
        __builtin_amdgcn_s_setprio(0); \
        SYNC_BOT; \
    }

    // prologue: prestage A0,B0 (T0 kk0), A1,B1 (T0 kk1), C0 (T1 kk0 X); drain.
    {
        int ko0 = xko(0), ko1 = xko(32), ko2 = xko(64);
        STGX(0, 0, ko0); STGW(0, 0, 0);
        STGX(0, 1, ko1); STGW(0, 1, 32);
        STGX(1, 0, ko2);
    }
    asm volatile("s_waitcnt vmcnt(0)" ::: "memory");
    __builtin_amdgcn_sched_barrier(0);
    __builtin_amdgcn_s_barrier();
    __builtin_amdgcn_sched_barrier(0);

    #pragma unroll 1
    for (int it = 0; it < NT / 2; ++it) {
        const int T1 = 2 * it + 1;
        int T2 = 2 * it + 2; if (T2 > NT - 1) T2 = NT - 1;   // clamped over-stage
        int T3 = 2 * it + 3; if (T3 > NT - 1) T3 = NT - 1;

        PH_A(0, 0, STGW(1, 0, T1 * 64));             // p1: D0 <- (T1,kk0) W
        PH_B(0, 0, STGX(1, 1, xko(T1 * 64 + 32)));   // p2: C1 <- (T1,kk1) X
        PH_A(0, 1, STGW(1, 1, T1 * 64 + 32));        // p3: D1 <- (T1,kk1) W
        PH_B(0, 1, STGX(0, 0, xko(T2 * 64)));        // p4: A0 <- (T2,kk0) X
        PH_A(1, 0, STGW(0, 0, T2 * 64));             // p5: B0 <- (T2,kk0) W
        PH_B(1, 0, STGX(0, 1, xko(T2 * 64 + 32)));   // p6: A1 <- (T2,kk1) X
        PH_A(1, 1, STGW(0, 1, T2 * 64 + 32));        // p7: B1 <- (T2,kk1) W
        PH_B(1, 1, STGX(1, 0, xko(T3 * 64)));        // p8: C0 <- (T3,kk0) X
    }

    // epilogue: C row=co (l4*4+r), col=px (l15)
    const int nimg = m0 / PIX;                // exact: 3136 = 14*224
    const int p0   = m0 - nimg * PIX;
    float* ob = out + nimg * (C_OUT * PIX);
    #pragma unroll
    for (int i = 0; i < 7; ++i) {
        int p = p0 + wpx * 112 + i * 16 + l15;
        #pragma unroll
        for (int j = 0; j < 4; ++j) {
            int co = wco * 64 + j * 16 + l4 * 4;
            #pragma unroll
            for (int r = 0; r < 4; ++r)
                ob[(co + r) * PIX + p] = acc[i][j][r];
        }
    }
#undef PH_A
#undef PH_B
#undef SYNC_TOP
#undef SYNC_BOT
#undef GLD
#undef STGX
#undef STGW
#undef LDXF
#undef LDWF
}

// ---------------- fallback: naive direct conv
__global__ void __launch_bounds__(256) conv_naive_kernel(const float* __restrict__ x,
                                                         const float* __restrict__ W,
                                                         float* __restrict__ out) {
    int idx = blockIdx.x * 256 + threadIdx.x;
    int w = idx % HW;
    int tmp = idx / HW;
    int h = tmp % HW;
    tmp /= HW;
    int co = tmp & 255;
    int n  = tmp >> 8;
    const float* xn = x + n * (C_IN * PIX);
    const float* wc = W + co * K_TOT;
    float acc = 0.f;
    for (int ci = 0; ci < C_IN; ++ci) {
        const float* xc = xn + ci * PIX;
        const float* wk = wc + ci * 9;
        #pragma unroll
        for (int kh = 0; kh < 3; ++kh) {
            int hh = h + kh - 1;
            if (hh < 0 || hh >= HW) continue;
            #pragma unroll
            for (int kw = 0; kw < 3; ++kw) {
                int ww = w + kw - 1;
                if (ww < 0 || ww >= HW) continue;
                float xv = xc[hh * HW + ww];
                acc += (wk[kh * 3 + kw] >= 0.f) ? xv : -xv;
            }
        }
    }
    out[idx] = acc;
}

extern "C" void kernel_launch(void* const* d_in, const int* in_sizes, int n_in,
                              void* d_out, int out_size, void* d_ws, size_t ws_size,
                              hipStream_t stream) {
    const float* x = (const float*)d_in[0];
    const float* W = (const float*)d_in[1];
    float* out = (float*)d_out;

    if (ws_size < (size_t)WS_NEEDED) {
        int total = N_IMG * C_OUT * PIX;
        conv_naive_kernel<<<(total + 255) / 256, 256, 0, stream>>>(x, W, out);
        return;
    }

    unsigned short* wb   = (unsigned short*)d_ws;
    __hip_bfloat16* xpad = (__hip_bfloat16*)((char*)d_ws + WB_BYTES);

    binW_kernel<<<(C_OUT * K_TOT) / 256, 256, 0, stream>>>(W, wb);
    transpose_pad_kernel<<<dim3(HW, N_IMG), 256, 0, stream>>>(x, (unsigned short*)xpad);
    conv_gemm_kernel<<<dim3(NBLK), 512, 0, stream>>>(xpad, (const __hip_bfloat16*)wb, out);
}